// Round 6
// baseline (561.274 us; speedup 1.0000x reference)
//
#include <hip/hip_runtime.h>

#define IN_DIM 256
#define CAP 10240   // per-bucket capacity; mean 8184, sigma ~90 -> 23-sigma margin
#define EPB 4096    // edges per scatter block

typedef _Float16 f16;
typedef _Float16 f16x8 __attribute__((ext_vector_type(8)));
typedef float f32x4 __attribute__((ext_vector_type(4)));
typedef unsigned u32x4 __attribute__((ext_vector_type(4)));
typedef unsigned u32x2 __attribute__((ext_vector_type(2)));

// ===================== bucketed CSR build (single-pass) =============

__global__ __launch_bounds__(256) void bucket_scatter_k(const int* __restrict__ srcp,
                                                        const int* __restrict__ dstp,
                                                        int* __restrict__ bcur,
                                                        unsigned* __restrict__ bedge, int E) {
    __shared__ int cnt[512], lstart[512], delta[512], fill[512];
    __shared__ int pfx[256];
    __shared__ unsigned spay[EPB];
    __shared__ unsigned char sbk[EPB];
    int tid = threadIdx.x;
    cnt[tid] = 0; cnt[tid + 256] = 0;
    fill[tid] = 0; fill[tid + 256] = 0;
    __syncthreads();
    size_t base = (size_t)blockIdx.x * EPB;
    int nloc = E - (int)base; if (nloc > EPB) nloc = EPB;
    int dreg[EPB / 256], sreg[EPB / 256];
#pragma unroll
    for (int j = 0; j < EPB / 256; j++) {
        int e = j * 256 + tid;
        if (e < nloc) {
            dreg[j] = dstp[base + e];
            sreg[j] = srcp[base + e];
            atomicAdd(&cnt[dreg[j] >> 8], 1);
        }
    }
    __syncthreads();
    int a0 = cnt[2 * tid], a1 = cnt[2 * tid + 1], s = a0 + a1;
    pfx[tid] = s;
    __syncthreads();
    for (int off = 1; off < 256; off <<= 1) {
        int t2 = (tid >= off) ? pfx[tid - off] : 0;
        __syncthreads();
        pfx[tid] += t2;
        __syncthreads();
    }
    int excl = pfx[tid] - s;
    lstart[2 * tid] = excl;
    lstart[2 * tid + 1] = excl + a0;
    int g0 = 0, g1 = 0;
    if (a0) g0 = atomicAdd(&bcur[2 * tid], a0);
    if (a1) g1 = atomicAdd(&bcur[2 * tid + 1], a1);
    delta[2 * tid]     = (2 * tid) * CAP + g0 - excl;
    delta[2 * tid + 1] = (2 * tid + 1) * CAP + g1 - (excl + a0);
    __syncthreads();
#pragma unroll
    for (int j = 0; j < EPB / 256; j++) {
        int e = j * 256 + tid;
        if (e < nloc) {
            int d = dreg[j], bk = d >> 8;
            int slot = lstart[bk] + atomicAdd(&fill[bk], 1);
            spay[slot] = (unsigned)sreg[j] | ((unsigned)(d & 255) << 17);
            sbk[slot] = (unsigned char)bk;
        }
    }
    __syncthreads();
    int mid = lstart[256];
#pragma unroll
    for (int j = 0; j < EPB / 256; j++) {
        int i = j * 256 + tid;
        if (i < nloc) {
            int bk = (int)sbk[i] | ((i >= mid) ? 256 : 0);
            int gp = i + delta[bk];
            if (gp < (bk + 1) * CAP)
                bedge[gp] = spay[i];
        }
    }
}

__global__ __launch_bounds__(256) void fine_sort_k(unsigned* __restrict__ bedge,
                                                   const int* __restrict__ bcur,
                                                   int2* __restrict__ ose, int Nn) {
    __shared__ int cnt[256], cur[256], pfx[256];
    __shared__ int sorted[CAP];
    int b = blockIdx.x, tid = threadIdx.x;
    int lo = b * CAP;
    int sz = bcur[b];
    if (sz > CAP) sz = CAP;
    cnt[tid] = 0;
    __syncthreads();
    for (int i = tid; i < sz; i += 256) atomicAdd(&cnt[bedge[lo + i] >> 17], 1);
    __syncthreads();
    int c = cnt[tid];
    pfx[tid] = c;
    __syncthreads();
    for (int off = 1; off < 256; off <<= 1) {
        int t2 = (tid >= off) ? pfx[tid - off] : 0;
        __syncthreads();
        pfx[tid] += t2;
        __syncthreads();
    }
    int excl = pfx[tid] - c;
    cur[tid] = excl;
    int node = b * 256 + tid;
    if (node < Nn) ose[node] = make_int2(lo + excl, lo + excl + c);
    __syncthreads();
    for (int i = tid; i < sz; i += 256) {
        unsigned v = bedge[lo + i];
        int slot = atomicAdd(&cur[v >> 17], 1);
        sorted[slot] = (int)(v & 0x1FFFFu);
    }
    __syncthreads();
    for (int i = tid; i < sz; i += 256) bedge[lo + i] = (unsigned)sorted[i];
}

// ==================== prep: zero bcur + weight prep =================
// Wt1  f16 [192][256] = [W1a | W1b_x]^T    bc1 f32 [192]
// Wt2  f16 [128][128] = [W2a | W2b_x]^T    bc2 f32 [128]
// Wmt1 f16 [128][64]  = W1b_m^T            Wmt2 f16 [64][64] = W2b_m^T

__global__ __launch_bounds__(256) void prep_k(
    const float* __restrict__ W1a, const float* __restrict__ W1b,
    const float* __restrict__ W2a, const float* __restrict__ W2b,
    const float* __restrict__ b1a, const float* __restrict__ b1b,
    const float* __restrict__ b2a, const float* __restrict__ b2b,
    f16* __restrict__ Wt1, f16* __restrict__ Wt2,
    f16* __restrict__ Wmt1, f16* __restrict__ Wmt2,
    float* __restrict__ bc1, float* __restrict__ bc2,
    int* __restrict__ bcur) {
    int tid = threadIdx.x;
    if (blockIdx.x == 0) { bcur[tid] = 0; bcur[tid + 256] = 0; }
    int i = blockIdx.x * 256 + tid;
    if (i < 49152) {
        int n = i >> 8, k = i & 255;
        Wt1[i] = (f16)(n < 64 ? W1a[k * 64 + n] : W1b[k * 128 + (n - 64)]);
    } else if (i < 65536) {
        int l = i - 49152; int n = l >> 7, k = l & 127;
        Wt2[l] = (f16)(n < 64 ? W2a[k * 64 + n] : W2b[k * 64 + (n - 64)]);
    } else if (i < 73728) {
        int l = i - 65536; int n = l >> 6, k = l & 63;
        Wmt1[l] = (f16)W1b[(256 + k) * 128 + n];
    } else if (i < 77824) {
        int l = i - 73728; int n = l >> 6, k = l & 63;
        Wmt2[l] = (f16)W2b[(128 + k) * 64 + n];
    } else if (i < 78016) {
        int l = i - 77824; bc1[l] = l < 64 ? b1a[l] : b1b[l - 64];
    } else if (i < 78144) {
        int l = i - 78016; bc2[l] = l < 64 ? b2a[l] : b2b[l - 64];
    }
}

// ===================== fused input GEMM (layer 1) ===================
// [Y1 | Y2] = x @ Wt1 + bc1; Y1 (message pre-act h, 64 dims) stored
// COLUMN-SLICED [4][Ns][16] so the gather's working set per slice is
// 3.2 MB (fits per-XCD 4 MB L2); Y2 (p partial, 128 dims) row-major.

__global__ __launch_bounds__(256) void gemm_fused192(const float* __restrict__ A1,
                                                     const f16* __restrict__ Wt,
                                                     const float* __restrict__ bc,
                                                     f16* __restrict__ Y1,
                                                     f16* __restrict__ Y2, int M) {
    constexpr int BN = 192, BM = 64, BK = 32, ASTR = BK + 8, K1 = 256;
    constexpr int WN = BN / 2, NB = WN / 16, SEGB = BN / 64;
    constexpr int EPS = BN + 8, TPR = BN / 8;
    constexpr size_t SM_AB = (size_t)BM * ASTR * 2 + (size_t)BN * ASTR * 2;
    constexpr size_t SM_EP = (size_t)BM * EPS * 2;
    constexpr size_t SM = SM_AB > SM_EP ? SM_AB : SM_EP;
    __shared__ __align__(16) char smem[SM];
    f16* As = reinterpret_cast<f16*>(smem);
    f16* Bs = reinterpret_cast<f16*>(smem + (size_t)BM * ASTR * 2);
    const int tid  = threadIdx.x;
    const int wave = tid >> 6, lane = tid & 63;
    const int wr = wave >> 1, wc = wave & 1;
    const int quad = lane >> 4, l16 = lane & 15;
    const int row0 = blockIdx.x * BM;

    f32x4 acc[2][NB];
#pragma unroll
    for (int i = 0; i < 2; i++)
#pragma unroll
        for (int j = 0; j < NB; j++) acc[i][j] = (f32x4)(0.f);

    const int ra = tid >> 2, sa = tid & 3;
    int rowA = row0 + ra;  if (rowA >= M) rowA = M - 1;

    u32x4 aReg, bReg[SEGB];
    auto loadA = [&](int kk) {
        const float* bp = A1 + (size_t)rowA * K1 + kk + sa * 8;
        f32x4 v0 = __builtin_nontemporal_load(reinterpret_cast<const f32x4*>(bp));
        f32x4 v1 = __builtin_nontemporal_load(reinterpret_cast<const f32x4*>(bp) + 1);
        union { f16 h[8]; u32x4 u; } p;
        p.h[0] = (f16)v0.x; p.h[1] = (f16)v0.y; p.h[2] = (f16)v0.z; p.h[3] = (f16)v0.w;
        p.h[4] = (f16)v1.x; p.h[5] = (f16)v1.y; p.h[6] = (f16)v1.z; p.h[7] = (f16)v1.w;
        aReg = p.u;
    };
    auto loadB = [&](int kk) {
#pragma unroll
        for (int i = 0; i < SEGB; i++) {
            int fid = tid + i * 256;
            int n = fid >> 2, s = fid & 3;
            bReg[i] = *reinterpret_cast<const u32x4*>(Wt + (size_t)n * K1 + kk + s * 8);
        }
    };

    loadA(0); loadB(0);
    for (int kk = 0; kk < K1; kk += BK) {
        *reinterpret_cast<u32x4*>(&As[ra * ASTR + sa * 8]) = aReg;
#pragma unroll
        for (int i = 0; i < SEGB; i++) {
            int fid = tid + i * 256;
            int n = fid >> 2, s = fid & 3;
            *reinterpret_cast<u32x4*>(&Bs[n * ASTR + s * 8]) = bReg[i];
        }
        __syncthreads();
        if (kk + BK < K1) { loadA(kk + BK); loadB(kk + BK); }
        f16x8 af[2], bf[NB];
#pragma unroll
        for (int rb = 0; rb < 2; rb++) {
            int row = wr * 32 + rb * 16 + l16;
            af[rb] = *reinterpret_cast<const f16x8*>(&As[row * ASTR + quad * 8]);
        }
#pragma unroll
        for (int cb = 0; cb < NB; cb++) {
            int n = wc * WN + cb * 16 + l16;
            bf[cb] = *reinterpret_cast<const f16x8*>(&Bs[n * ASTR + quad * 8]);
        }
#pragma unroll
        for (int rb = 0; rb < 2; rb++)
#pragma unroll
            for (int cb = 0; cb < NB; cb++)
                acc[rb][cb] = __builtin_amdgcn_mfma_f32_16x16x32_f16(af[rb], bf[cb], acc[rb][cb], 0, 0, 0);
        __syncthreads();
    }

    f16* ep = reinterpret_cast<f16*>(smem);
#pragma unroll
    for (int rb = 0; rb < 2; rb++) {
#pragma unroll
        for (int cb = 0; cb < NB; cb++) {
            int col = wc * WN + cb * 16 + l16;
            float bv = bc[col];
#pragma unroll
            for (int r = 0; r < 4; r++) {
                int lrow = wr * 32 + rb * 16 + quad * 4 + r;
                ep[(size_t)lrow * EPS + col] = (f16)(acc[rb][cb][r] + bv);
            }
        }
    }
    __syncthreads();
#pragma unroll
    for (int p = 0; p < BM * TPR / 256; p++) {
        int fid = p * 256 + tid;
        int row = fid / TPR, c = fid % TPR, col0 = c * 8;
        int grow = row0 + row;
        if (grow < M) {
            u32x4 val = *reinterpret_cast<const u32x4*>(&ep[(size_t)row * EPS + col0]);
            if (col0 < 64) {
                // sliced store: slice = col0>>4, offset (col0&15)
                f16* dst = Y1 + (size_t)(col0 >> 4) * M * 16 + (size_t)grow * 16 + (col0 & 15);
                *reinterpret_cast<u32x4*>(dst) = val;
            } else {
                __builtin_nontemporal_store(val,
                    reinterpret_cast<u32x4*>(Y2 + (size_t)grow * 128 + (col0 - 64)));
            }
        }
    }
}

// =============== sliced mean aggregation (CSR gather) ===============
// One wave per (node, slice): slice = blockIdx.y (grid slice-major so
// concurrent blocks share one 3.2 MB slice -> L2-resident gather).
// 4 lanes per row-slice (8B each = 16 dims), 16 rows in flight.

__global__ __launch_bounds__(256) void aggr_k(const int2* __restrict__ ose,
                                              const int* __restrict__ ssrc,
                                              const f16* __restrict__ h,
                                              f16* __restrict__ m, int n) {
    const int slice = blockIdx.y;
    const int node = blockIdx.x * 4 + (threadIdx.x >> 6);
    const int lane = threadIdx.x & 63;
    if (node >= n) return;
    int2 se = ose[node];
    int s0 = se.x, s1 = se.y;
    const int l4 = lane & 3, r16 = lane >> 2;
    const u32x2* hp = reinterpret_cast<const u32x2*>(h + (size_t)slice * n * 16);
    float a0 = 0.f, a1 = 0.f, a2 = 0.f, a3 = 0.f;
    auto accum = [&](u32x2 u) {
        union { u32x2 u; f16 hh[4]; } p; p.u = u;
        a0 += (float)p.hh[0]; a1 += (float)p.hh[1];
        a2 += (float)p.hh[2]; a3 += (float)p.hh[3];
    };
    for (int c = s0; c < s1; c += 64) {
        int cn = min(64, s1 - c);
        int myidx = (lane < cn) ? ssrc[c + lane] : 0;
        int t = 0;
        for (; t + 32 <= cn; t += 32) {
            int ia = __shfl(myidx, t + r16);
            int ib = __shfl(myidx, t + 16 + r16);
            u32x2 ua = hp[(size_t)ia * 4 + l4];
            u32x2 ub = hp[(size_t)ib * 4 + l4];
            accum(ua); accum(ub);
        }
        if (t + 16 <= cn) {
            int ia = __shfl(myidx, t + r16);
            accum(hp[(size_t)ia * 4 + l4]);
            t += 16;
        }
        if (t < cn) {
            int r = t + r16;
            int rr = (r < cn) ? r : (cn - 1);
            int ia = __shfl(myidx, rr);
            if (r < cn) accum(hp[(size_t)ia * 4 + l4]);
        }
    }
    // butterfly over the 16 row-groups (lane bits 2..5)
    a0 += __shfl_xor(a0, 4);  a1 += __shfl_xor(a1, 4);  a2 += __shfl_xor(a2, 4);  a3 += __shfl_xor(a3, 4);
    a0 += __shfl_xor(a0, 8);  a1 += __shfl_xor(a1, 8);  a2 += __shfl_xor(a2, 8);  a3 += __shfl_xor(a3, 8);
    a0 += __shfl_xor(a0, 16); a1 += __shfl_xor(a1, 16); a2 += __shfl_xor(a2, 16); a3 += __shfl_xor(a3, 16);
    a0 += __shfl_xor(a0, 32); a1 += __shfl_xor(a1, 32); a2 += __shfl_xor(a2, 32); a3 += __shfl_xor(a3, 32);
    if (lane < 4) {
        float inv = 1.0f / fmaxf((float)(s1 - s0), 1.0f);
        union { u32x2 u; f16 hh[4]; } pk;
        pk.hh[0] = (f16)(a0 * inv); pk.hh[1] = (f16)(a1 * inv);
        pk.hh[2] = (f16)(a2 * inv); pk.hh[3] = (f16)(a3 * inv);
        u32x2* mp = reinterpret_cast<u32x2*>(m + (size_t)slice * n * 16 + (size_t)node * 16);
        mp[l4] = pk.u;
    }
}

// ========= fused combine1 + GEMM2: x1 lives only in LDS =============
// Phase 1: x1_tile = relu(P + M@Wmt1)   (64 x 128, K=64, 2 MFMA steps)
// Phase 2: [h2 | p2] = x1_tile @ Wt2 + bc2  (K=128, BK=32 loop)
// h2 stored sliced [4][M][16]; p2 row-major.

__global__ __launch_bounds__(256) void comb_gemm_k(const f16* __restrict__ Mb,  // sliced [4][M][16]
                                                   const f16* __restrict__ Wmt, // [128][64]
                                                   const f16* __restrict__ P,   // [M][128]
                                                   const f16* __restrict__ Wt2, // [128][128]
                                                   const float* __restrict__ bc2,
                                                   f16* __restrict__ H2,        // sliced [4][M][16]
                                                   f16* __restrict__ P2,        // [M][64]
                                                   int M) {
    constexpr int BM = 64, ASTR = 72, TSTR = 136, BSTR = 40;
    constexpr int BN1 = 128, NB1 = 4;   // phase-1 cols, 2x2 waves, WN=64
    constexpr int BN2 = 128, NB2c = 4;  // phase-2 cols
    // LDS plan: phase1 As[64*72] @0 (9216B), Bs1[128*72] @9216 (18432B) = 27648
    //           phase2 tile[64*136] @0 (17408B), Bs2[128*40] @17408 (10240B) = 27648
    __shared__ __align__(16) char smem[27648];
    f16* As  = reinterpret_cast<f16*>(smem);
    f16* Bs1 = reinterpret_cast<f16*>(smem + (size_t)BM * ASTR * 2);
    f16* tile = reinterpret_cast<f16*>(smem);
    f16* Bs2 = reinterpret_cast<f16*>(smem + (size_t)BM * TSTR * 2);
    const int tid  = threadIdx.x;
    const int wave = tid >> 6, lane = tid & 63;
    const int wr = wave >> 1, wc = wave & 1;
    const int quad = lane >> 4, l16 = lane & 15;
    const int row0 = blockIdx.x * BM;

    // ---- phase 1 staging: A (64x64 from sliced Mb), B1 (Wmt 128x64) ----
#pragma unroll
    for (int fid = tid; fid < 512; fid += 256) {
        int row = fid >> 3, s = fid & 7;
        int grow = row0 + row; if (grow >= M) grow = M - 1;
        const f16* src = Mb + (size_t)(s >> 1) * M * 16 + (size_t)grow * 16 + (s & 1) * 8;
        *reinterpret_cast<u32x4*>(&As[row * ASTR + s * 8]) =
            *reinterpret_cast<const u32x4*>(src);
    }
#pragma unroll
    for (int fid = tid; fid < BN1 * 8; fid += 256) {
        int n = fid >> 3, s = fid & 7;
        *reinterpret_cast<u32x4*>(&Bs1[n * ASTR + s * 8]) =
            *reinterpret_cast<const u32x4*>(Wmt + (size_t)n * 64 + s * 8);
    }
    __syncthreads();

    f32x4 acc[2][NB1];
#pragma unroll
    for (int i = 0; i < 2; i++)
#pragma unroll
        for (int j = 0; j < NB1; j++) acc[i][j] = (f32x4)(0.f);
#pragma unroll
    for (int ks = 0; ks < 2; ks++) {
        f16x8 af[2], bf[NB1];
#pragma unroll
        for (int rb = 0; rb < 2; rb++) {
            int row = wr * 32 + rb * 16 + l16;
            af[rb] = *reinterpret_cast<const f16x8*>(&As[row * ASTR + ks * 32 + quad * 8]);
        }
#pragma unroll
        for (int cb = 0; cb < NB1; cb++) {
            int n = wc * 64 + cb * 16 + l16;
            bf[cb] = *reinterpret_cast<const f16x8*>(&Bs1[n * ASTR + ks * 32 + quad * 8]);
        }
#pragma unroll
        for (int rb = 0; rb < 2; rb++)
#pragma unroll
            for (int cb = 0; cb < NB1; cb++)
                acc[rb][cb] = __builtin_amdgcn_mfma_f32_16x16x32_f16(af[rb], bf[cb], acc[rb][cb], 0, 0, 0);
    }
    __syncthreads();

    // ---- x1 tile: relu(P + acc), f16 (identical rounding to stored x1) ----
#pragma unroll
    for (int rb = 0; rb < 2; rb++) {
#pragma unroll
        for (int cb = 0; cb < NB1; cb++) {
            int col = wc * 64 + cb * 16 + l16;
#pragma unroll
            for (int r = 0; r < 4; r++) {
                int lrow = wr * 32 + rb * 16 + quad * 4 + r;
                int grow = row0 + lrow;
                float pv = (grow < M) ? (float)P[(size_t)grow * 128 + col] : 0.f;
                tile[(size_t)lrow * TSTR + col] = (f16)fmaxf(acc[rb][cb][r] + pv, 0.f);
            }
        }
    }
    // (tile readers wait at the first in-loop barrier below)

    // ---- phase 2: [h2|p2] = tile @ Wt2 + bc2, K=128 ----
    f32x4 acc2[2][NB2c];
#pragma unroll
    for (int i = 0; i < 2; i++)
#pragma unroll
        for (int j = 0; j < NB2c; j++) acc2[i][j] = (f32x4)(0.f);

    u32x4 bReg[2];
    auto loadB2 = [&](int kk) {
#pragma unroll
        for (int i = 0; i < 2; i++) {
            int fid = tid + i * 256;
            int n = fid >> 2, s = fid & 3;
            bReg[i] = *reinterpret_cast<const u32x4*>(Wt2 + (size_t)n * 128 + kk + s * 8);
        }
    };
    loadB2(0);
    for (int kk = 0; kk < 128; kk += 32) {
#pragma unroll
        for (int i = 0; i < 2; i++) {
            int fid = tid + i * 256;
            int n = fid >> 2, s = fid & 3;
            *reinterpret_cast<u32x4*>(&Bs2[n * BSTR + s * 8]) = bReg[i];
        }
        __syncthreads();           // also orders tile writes before tile reads
        if (kk + 32 < 128) loadB2(kk + 32);
        f16x8 af[2], bf[NB2c];
#pragma unroll
        for (int rb = 0; rb < 2; rb++) {
            int row = wr * 32 + rb * 16 + l16;
            af[rb] = *reinterpret_cast<const f16x8*>(&tile[(size_t)row * TSTR + kk + quad * 8]);
        }
#pragma unroll
        for (int cb = 0; cb < NB2c; cb++) {
            int n = wc * 64 + cb * 16 + l16;
            bf[cb] = *reinterpret_cast<const f16x8*>(&Bs2[n * BSTR + quad * 8]);
        }
#pragma unroll
        for (int rb = 0; rb < 2; rb++)
#pragma unroll
            for (int cb = 0; cb < NB2c; cb++)
                acc2[rb][cb] = __builtin_amdgcn_mfma_f32_16x16x32_f16(af[rb], bf[cb], acc2[rb][cb], 0, 0, 0);
        __syncthreads();
    }

    // ---- epilogue: bias (no act) -> LDS (over tile) -> stores ----
    f16* ep = tile;
#pragma unroll
    for (int rb = 0; rb < 2; rb++) {
#pragma unroll
        for (int cb = 0; cb < NB2c; cb++) {
            int col = wc * 64 + cb * 16 + l16;
            float bv = bc2[col];
#pragma unroll
            for (int r = 0; r < 4; r++) {
                int lrow = wr * 32 + rb * 16 + quad * 4 + r;
                ep[(size_t)lrow * TSTR + col] = (f16)(acc2[rb][cb][r] + bv);
            }
        }
    }
    __syncthreads();
#pragma unroll
    for (int p = 0; p < 4; p++) {                 // 64 rows * 16 chunks / 256
        int fid = p * 256 + tid;
        int row = fid >> 4, c = fid & 15, col0 = c * 8;
        int grow = row0 + row;
        if (grow < M) {
            u32x4 val = *reinterpret_cast<const u32x4*>(&ep[(size_t)row * TSTR + col0]);
            if (col0 < 64) {
                f16* dst = H2 + (size_t)(col0 >> 4) * M * 16 + (size_t)grow * 16 + (col0 & 15);
                *reinterpret_cast<u32x4*>(dst) = val;
            } else {
                __builtin_nontemporal_store(val,
                    reinterpret_cast<u32x4*>(P2 + (size_t)grow * 64 + (col0 - 64)));
            }
        }
    }
}

// ============ combine2 + head: out = MLP(relu(P2 + M@Wmt2)) =========

__global__ __launch_bounds__(256) void comb_head_k(const f16* __restrict__ Mb,  // sliced [4][M][16]
                                                   const f16* __restrict__ Wmt, // [64][64]
                                                   const f16* __restrict__ P,   // [M][64]
                                                   const float* __restrict__ Wl1,
                                                   const float* __restrict__ bl1,
                                                   const float* __restrict__ Wl2,
                                                   const float* __restrict__ bl2,
                                                   float* __restrict__ out, int M) {
    constexpr int BM = 64, ASTR = 72, BN = 64, NB = 2;
    constexpr int EPS = BN + 8;
    constexpr size_t SZ_A = (size_t)BM * ASTR * 2;
    constexpr size_t SM_AB = SZ_A + (size_t)BN * ASTR * 2;
    constexpr size_t SM_EP = (size_t)BM * EPS * 2;
    constexpr size_t SM_CORE = SM_AB > SM_EP ? SM_AB : SM_EP;
    __shared__ __align__(16) char smem[SM_CORE + (2048 + 64) * 4];
    f16* As = reinterpret_cast<f16*>(smem);
    f16* Bs = reinterpret_cast<f16*>(smem + SZ_A);
    const int tid  = threadIdx.x;
    const int wave = tid >> 6, lane = tid & 63;
    const int wr = wave >> 1, wc = wave & 1;
    const int quad = lane >> 4, l16 = lane & 15;
    const int row0 = blockIdx.x * BM;

#pragma unroll
    for (int fid = tid; fid < 512; fid += 256) {
        int row = fid >> 3, s = fid & 7;
        int grow = row0 + row; if (grow >= M) grow = M - 1;
        const f16* src = Mb + (size_t)(s >> 1) * M * 16 + (size_t)grow * 16 + (s & 1) * 8;
        *reinterpret_cast<u32x4*>(&As[row * ASTR + s * 8]) =
            *reinterpret_cast<const u32x4*>(src);
    }
    for (int fid = tid; fid < BN * 8; fid += 256) {
        int n = fid >> 3, s = fid & 7;
        *reinterpret_cast<u32x4*>(&Bs[n * ASTR + s * 8]) =
            *reinterpret_cast<const u32x4*>(Wmt + (size_t)n * 64 + s * 8);
    }
    {
        float* w1s = reinterpret_cast<float*>(smem + SM_CORE);
        for (int t2 = tid; t2 < 2048; t2 += 256) w1s[t2] = Wl1[t2];
        if (tid < 32) { w1s[2048 + tid] = bl1[tid]; w1s[2048 + 32 + tid] = Wl2[tid]; }
    }
    __syncthreads();

    f32x4 acc[2][NB];
#pragma unroll
    for (int i = 0; i < 2; i++)
#pragma unroll
        for (int j = 0; j < NB; j++) acc[i][j] = (f32x4)(0.f);
#pragma unroll
    for (int ks = 0; ks < 2; ks++) {
        f16x8 af[2], bf[NB];
#pragma unroll
        for (int rb = 0; rb < 2; rb++) {
            int row = wr * 32 + rb * 16 + l16;
            af[rb] = *reinterpret_cast<const f16x8*>(&As[row * ASTR + ks * 32 + quad * 8]);
        }
#pragma unroll
        for (int cb = 0; cb < NB; cb++) {
            int n = wc * 32 + cb * 16 + l16;
            bf[cb] = *reinterpret_cast<const f16x8*>(&Bs[n * ASTR + ks * 32 + quad * 8]);
        }
#pragma unroll
        for (int rb = 0; rb < 2; rb++)
#pragma unroll
            for (int cb = 0; cb < NB; cb++)
                acc[rb][cb] = __builtin_amdgcn_mfma_f32_16x16x32_f16(af[rb], bf[cb], acc[rb][cb], 0, 0, 0);
    }
    __syncthreads();

    f16* ep = reinterpret_cast<f16*>(smem);
#pragma unroll
    for (int rb = 0; rb < 2; rb++) {
#pragma unroll
        for (int cb = 0; cb < NB; cb++) {
            int col = wc * 32 + cb * 16 + l16;
#pragma unroll
            for (int r = 0; r < 4; r++) {
                int lrow = wr * 32 + rb * 16 + quad * 4 + r;
                int grow = row0 + lrow;
                float pv = (grow < M) ? (float)P[(size_t)grow * 64 + col] : 0.f;
                ep[(size_t)lrow * EPS + col] = (f16)fmaxf(acc[rb][cb][r] + pv, 0.f);
            }
        }
    }
    __syncthreads();

    float* w1s = reinterpret_cast<float*>(smem + SM_CORE);
    float* b1s = w1s + 2048;
    float* w2s = b1s + 32;
    int row = tid >> 2, part = tid & 3;
    const f16* eprow = ep + (size_t)row * EPS;
    float hj[8];
#pragma unroll
    for (int j = 0; j < 8; j++) hj[j] = b1s[part * 8 + j];
    for (int k = 0; k < 64; k++) {
        float v = (float)eprow[k];
        const float* wrow = &w1s[k * 32 + part * 8];
#pragma unroll
        for (int j = 0; j < 8; j++) hj[j] += v * wrow[j];
    }
    float o = 0.f;
#pragma unroll
    for (int j = 0; j < 8; j++) o += fmaxf(hj[j], 0.f) * w2s[part * 8 + j];
    o += __shfl_xor(o, 1);
    o += __shfl_xor(o, 2);
    int grow = row0 + row;
    if (part == 0 && grow < M) out[grow] = o + bl2[0];
}

// ============================ launch ================================

extern "C" void kernel_launch(void* const* d_in, const int* in_sizes, int n_in,
                              void* d_out, int out_size, void* d_ws, size_t ws_size,
                              hipStream_t stream) {
    const float* x   = (const float*)d_in[0];
    const int*   ei  = (const int*)d_in[1];
    const float* W1a = (const float*)d_in[3];
    const float* b1a = (const float*)d_in[4];
    const float* W1b = (const float*)d_in[5];
    const float* b1b = (const float*)d_in[6];
    const float* W2a = (const float*)d_in[7];
    const float* b2a = (const float*)d_in[8];
    const float* W2b = (const float*)d_in[9];
    const float* b2b = (const float*)d_in[10];
    const float* Wl1 = (const float*)d_in[11];
    const float* bl1 = (const float*)d_in[12];
    const float* Wl2 = (const float*)d_in[13];
    const float* bl2 = (const float*)d_in[14];

    const int N = in_sizes[0] / IN_DIM;
    const int E = in_sizes[1] / 2;
    const int* srcp = ei;
    const int* dstp = ei + E;

    char* ws = (char*)d_ws;
    size_t off = 0;
    auto alloc = [&](size_t bytes) -> char* {
        char* p = ws + off;
        off = (off + bytes + 255) & ~(size_t)255;
        return p;
    };
    int NB2 = (N + 255) / 256;
    int*      bcur  = (int*)alloc(512 * 4);
    unsigned* bedge = (unsigned*)alloc((size_t)NB2 * CAP * 4);
    int2*     ose   = (int2*)alloc((size_t)N * 8);
    f16*      hbuf  = (f16*)alloc((size_t)N * 64 * 2);   // sliced [4][N][16]
    f16*      mbuf  = (f16*)alloc((size_t)N * 64 * 2);   // sliced [4][N][16]
    f16*      pbuf  = (f16*)alloc((size_t)N * 128 * 2);
    f16*      h2    = (f16*)alloc((size_t)N * 64 * 2);   // sliced [4][N][16]
    f16*      p2    = (f16*)alloc((size_t)N * 64 * 2);
    f16*      Wt1   = (f16*)alloc(192 * 256 * 2);
    f16*      Wt2   = (f16*)alloc(128 * 128 * 2);
    f16*      Wmt1  = (f16*)alloc(128 * 64 * 2);
    f16*      Wmt2  = (f16*)alloc(64 * 64 * 2);
    float*    bc1   = (float*)alloc(192 * 4);
    float*    bc2   = (float*)alloc(128 * 4);
    (void)ws_size;

    // ---- prep (zero bcur + weights) then CSR build ----
    prep_k<<<306, 256, 0, stream>>>(W1a, W1b, W2a, W2b, b1a, b1b, b2a, b2b,
                                    Wt1, Wt2, Wmt1, Wmt2, bc1, bc2, bcur);
    int ebk = (E + EPB - 1) / EPB;
    bucket_scatter_k<<<ebk, 256, 0, stream>>>(srcp, dstp, bcur, bedge, E);
    fine_sort_k<<<NB2, 256, 0, stream>>>(bedge, bcur, ose, N);

    int mb = (N + 63) / 64;
    dim3 ag((N + 3) / 4, 4);          // x: node blocks (4 waves), y: slice
    const int* ssrc = (const int*)bedge;

    // ---- conv1: x -> [h|p] (h sliced); sliced gather; combine+gemm2 ----
    gemm_fused192<<<mb, 256, 0, stream>>>(x, Wt1, bc1, hbuf, pbuf, N);
    aggr_k<<<ag, 256, 0, stream>>>(ose, ssrc, hbuf, mbuf, N);
    comb_gemm_k<<<mb, 256, 0, stream>>>(mbuf, Wmt1, pbuf, Wt2, bc2, h2, p2, N);

    // ---- conv2 tail: sliced gather; combine+head ----
    aggr_k<<<ag, 256, 0, stream>>>(ose, ssrc, h2, mbuf, N);
    comb_head_k<<<mb, 256, 0, stream>>>(mbuf, Wmt2, p2, Wl1, bl1, Wl2, bl2,
                                        (float*)d_out, N);
}

// Round 7
// 436.008 us; speedup vs baseline: 1.2873x; 1.2873x over previous
//
#include <hip/hip_runtime.h>

#define IN_DIM 256
#define CAP 10240   // per-bucket capacity; mean 8184, sigma ~90 -> 23-sigma margin
#define EPB 4096    // edges per scatter block

typedef _Float16 f16;
typedef _Float16 f16x8 __attribute__((ext_vector_type(8)));
typedef float f32x4 __attribute__((ext_vector_type(4)));
typedef unsigned u32x4 __attribute__((ext_vector_type(4)));
typedef unsigned u32x2 __attribute__((ext_vector_type(2)));

// ===================== bucketed CSR build (single-pass) =============

__global__ __launch_bounds__(256) void bucket_scatter_k(const int* __restrict__ srcp,
                                                        const int* __restrict__ dstp,
                                                        int* __restrict__ bcur,
                                                        unsigned* __restrict__ bedge, int E) {
    __shared__ int cnt[512], lstart[512], delta[512], fill[512];
    __shared__ int pfx[256];
    __shared__ unsigned spay[EPB];
    __shared__ unsigned char sbk[EPB];
    int tid = threadIdx.x;
    cnt[tid] = 0; cnt[tid + 256] = 0;
    fill[tid] = 0; fill[tid + 256] = 0;
    __syncthreads();
    size_t base = (size_t)blockIdx.x * EPB;
    int nloc = E - (int)base; if (nloc > EPB) nloc = EPB;
    int dreg[EPB / 256], sreg[EPB / 256];
#pragma unroll
    for (int j = 0; j < EPB / 256; j++) {
        int e = j * 256 + tid;
        if (e < nloc) {
            dreg[j] = dstp[base + e];
            sreg[j] = srcp[base + e];
            atomicAdd(&cnt[dreg[j] >> 8], 1);
        }
    }
    __syncthreads();
    int a0 = cnt[2 * tid], a1 = cnt[2 * tid + 1], s = a0 + a1;
    pfx[tid] = s;
    __syncthreads();
    for (int off = 1; off < 256; off <<= 1) {
        int t2 = (tid >= off) ? pfx[tid - off] : 0;
        __syncthreads();
        pfx[tid] += t2;
        __syncthreads();
    }
    int excl = pfx[tid] - s;
    lstart[2 * tid] = excl;
    lstart[2 * tid + 1] = excl + a0;
    int g0 = 0, g1 = 0;
    if (a0) g0 = atomicAdd(&bcur[2 * tid], a0);
    if (a1) g1 = atomicAdd(&bcur[2 * tid + 1], a1);
    delta[2 * tid]     = (2 * tid) * CAP + g0 - excl;
    delta[2 * tid + 1] = (2 * tid + 1) * CAP + g1 - (excl + a0);
    __syncthreads();
#pragma unroll
    for (int j = 0; j < EPB / 256; j++) {
        int e = j * 256 + tid;
        if (e < nloc) {
            int d = dreg[j], bk = d >> 8;
            int slot = lstart[bk] + atomicAdd(&fill[bk], 1);
            spay[slot] = (unsigned)sreg[j] | ((unsigned)(d & 255) << 17);
            sbk[slot] = (unsigned char)bk;
        }
    }
    __syncthreads();
    int mid = lstart[256];
#pragma unroll
    for (int j = 0; j < EPB / 256; j++) {
        int i = j * 256 + tid;
        if (i < nloc) {
            int bk = (int)sbk[i] | ((i >= mid) ? 256 : 0);
            int gp = i + delta[bk];
            if (gp < (bk + 1) * CAP)
                bedge[gp] = spay[i];
        }
    }
}

__global__ __launch_bounds__(256) void fine_sort_k(unsigned* __restrict__ bedge,
                                                   const int* __restrict__ bcur,
                                                   int2* __restrict__ ose, int Nn) {
    __shared__ int cnt[256], cur[256], pfx[256];
    __shared__ int sorted[CAP];
    int b = blockIdx.x, tid = threadIdx.x;
    int lo = b * CAP;
    int sz = bcur[b];
    if (sz > CAP) sz = CAP;
    cnt[tid] = 0;
    __syncthreads();
    for (int i = tid; i < sz; i += 256) atomicAdd(&cnt[bedge[lo + i] >> 17], 1);
    __syncthreads();
    int c = cnt[tid];
    pfx[tid] = c;
    __syncthreads();
    for (int off = 1; off < 256; off <<= 1) {
        int t2 = (tid >= off) ? pfx[tid - off] : 0;
        __syncthreads();
        pfx[tid] += t2;
        __syncthreads();
    }
    int excl = pfx[tid] - c;
    cur[tid] = excl;
    int node = b * 256 + tid;
    if (node < Nn) ose[node] = make_int2(lo + excl, lo + excl + c);
    __syncthreads();
    for (int i = tid; i < sz; i += 256) {
        unsigned v = bedge[lo + i];
        int slot = atomicAdd(&cur[v >> 17], 1);
        sorted[slot] = (int)(v & 0x1FFFFu);
    }
    __syncthreads();
    for (int i = tid; i < sz; i += 256) bedge[lo + i] = (unsigned)sorted[i];
}

// ==================== prep: zero bcur + weight prep =================
// Wt1  f16 [192][256] = [W1a | W1b_x]^T    bc1 f32 [192]
// Wt2  f16 [128][128] = [W2a | W2b_x]^T    bc2 f32 [128]
// Wmt1 f16 [128][64]  = W1b_m^T            Wmt2 f16 [64][64] = W2b_m^T

__global__ __launch_bounds__(256) void prep_k(
    const float* __restrict__ W1a, const float* __restrict__ W1b,
    const float* __restrict__ W2a, const float* __restrict__ W2b,
    const float* __restrict__ b1a, const float* __restrict__ b1b,
    const float* __restrict__ b2a, const float* __restrict__ b2b,
    f16* __restrict__ Wt1, f16* __restrict__ Wt2,
    f16* __restrict__ Wmt1, f16* __restrict__ Wmt2,
    float* __restrict__ bc1, float* __restrict__ bc2,
    int* __restrict__ bcur) {
    int tid = threadIdx.x;
    if (blockIdx.x == 0) { bcur[tid] = 0; bcur[tid + 256] = 0; }
    int i = blockIdx.x * 256 + tid;
    if (i < 49152) {
        int n = i >> 8, k = i & 255;
        Wt1[i] = (f16)(n < 64 ? W1a[k * 64 + n] : W1b[k * 128 + (n - 64)]);
    } else if (i < 65536) {
        int l = i - 49152; int n = l >> 7, k = l & 127;
        Wt2[l] = (f16)(n < 64 ? W2a[k * 64 + n] : W2b[k * 64 + (n - 64)]);
    } else if (i < 73728) {
        int l = i - 65536; int n = l >> 6, k = l & 63;
        Wmt1[l] = (f16)W1b[(256 + k) * 128 + n];
    } else if (i < 77824) {
        int l = i - 73728; int n = l >> 6, k = l & 63;
        Wmt2[l] = (f16)W2b[(128 + k) * 64 + n];
    } else if (i < 78016) {
        int l = i - 77824; bc1[l] = l < 64 ? b1a[l] : b1b[l - 64];
    } else if (i < 78144) {
        int l = i - 78016; bc2[l] = l < 64 ? b2a[l] : b2b[l - 64];
    }
}

// ===================== fused input GEMM (layer 1) ===================
// [Y1 | Y2] = x @ Wt1 + bc1; Y1 = message pre-act h (row-major [M][64]),
// Y2 = x-part partial p with bias folded in ([M][128], nontemporal).

__global__ __launch_bounds__(256) void gemm_fused192(const float* __restrict__ A1,
                                                     const f16* __restrict__ Wt,
                                                     const float* __restrict__ bc,
                                                     f16* __restrict__ Y1,
                                                     f16* __restrict__ Y2, int M) {
    constexpr int BN = 192, BM = 64, BK = 32, ASTR = BK + 8, K1 = 256;
    constexpr int WN = BN / 2, NB = WN / 16, SEGB = BN / 64;
    constexpr int EPS = BN + 8, TPR = BN / 8;
    constexpr size_t SM_AB = (size_t)BM * ASTR * 2 + (size_t)BN * ASTR * 2;
    constexpr size_t SM_EP = (size_t)BM * EPS * 2;
    constexpr size_t SM = SM_AB > SM_EP ? SM_AB : SM_EP;
    __shared__ __align__(16) char smem[SM];
    f16* As = reinterpret_cast<f16*>(smem);
    f16* Bs = reinterpret_cast<f16*>(smem + (size_t)BM * ASTR * 2);
    const int tid  = threadIdx.x;
    const int wave = tid >> 6, lane = tid & 63;
    const int wr = wave >> 1, wc = wave & 1;
    const int quad = lane >> 4, l16 = lane & 15;
    const int row0 = blockIdx.x * BM;

    f32x4 acc[2][NB];
#pragma unroll
    for (int i = 0; i < 2; i++)
#pragma unroll
        for (int j = 0; j < NB; j++) acc[i][j] = (f32x4)(0.f);

    const int ra = tid >> 2, sa = tid & 3;
    int rowA = row0 + ra;  if (rowA >= M) rowA = M - 1;

    u32x4 aReg, bReg[SEGB];
    auto loadA = [&](int kk) {
        const float* bp = A1 + (size_t)rowA * K1 + kk + sa * 8;
        f32x4 v0 = __builtin_nontemporal_load(reinterpret_cast<const f32x4*>(bp));
        f32x4 v1 = __builtin_nontemporal_load(reinterpret_cast<const f32x4*>(bp) + 1);
        union { f16 h[8]; u32x4 u; } p;
        p.h[0] = (f16)v0.x; p.h[1] = (f16)v0.y; p.h[2] = (f16)v0.z; p.h[3] = (f16)v0.w;
        p.h[4] = (f16)v1.x; p.h[5] = (f16)v1.y; p.h[6] = (f16)v1.z; p.h[7] = (f16)v1.w;
        aReg = p.u;
    };
    auto loadB = [&](int kk) {
#pragma unroll
        for (int i = 0; i < SEGB; i++) {
            int fid = tid + i * 256;
            int n = fid >> 2, s = fid & 3;
            bReg[i] = *reinterpret_cast<const u32x4*>(Wt + (size_t)n * K1 + kk + s * 8);
        }
    };

    loadA(0); loadB(0);
    for (int kk = 0; kk < K1; kk += BK) {
        *reinterpret_cast<u32x4*>(&As[ra * ASTR + sa * 8]) = aReg;
#pragma unroll
        for (int i = 0; i < SEGB; i++) {
            int fid = tid + i * 256;
            int n = fid >> 2, s = fid & 3;
            *reinterpret_cast<u32x4*>(&Bs[n * ASTR + s * 8]) = bReg[i];
        }
        __syncthreads();
        if (kk + BK < K1) { loadA(kk + BK); loadB(kk + BK); }
        f16x8 af[2], bf[NB];
#pragma unroll
        for (int rb = 0; rb < 2; rb++) {
            int row = wr * 32 + rb * 16 + l16;
            af[rb] = *reinterpret_cast<const f16x8*>(&As[row * ASTR + quad * 8]);
        }
#pragma unroll
        for (int cb = 0; cb < NB; cb++) {
            int n = wc * WN + cb * 16 + l16;
            bf[cb] = *reinterpret_cast<const f16x8*>(&Bs[n * ASTR + quad * 8]);
        }
#pragma unroll
        for (int rb = 0; rb < 2; rb++)
#pragma unroll
            for (int cb = 0; cb < NB; cb++)
                acc[rb][cb] = __builtin_amdgcn_mfma_f32_16x16x32_f16(af[rb], bf[cb], acc[rb][cb], 0, 0, 0);
        __syncthreads();
    }

    f16* ep = reinterpret_cast<f16*>(smem);
#pragma unroll
    for (int rb = 0; rb < 2; rb++) {
#pragma unroll
        for (int cb = 0; cb < NB; cb++) {
            int col = wc * WN + cb * 16 + l16;
            float bv = bc[col];
#pragma unroll
            for (int r = 0; r < 4; r++) {
                int lrow = wr * 32 + rb * 16 + quad * 4 + r;
                ep[(size_t)lrow * EPS + col] = (f16)(acc[rb][cb][r] + bv);
            }
        }
    }
    __syncthreads();
#pragma unroll
    for (int p = 0; p < BM * TPR / 256; p++) {
        int fid = p * 256 + tid;
        int row = fid / TPR, c = fid % TPR, col0 = c * 8;
        int grow = row0 + row;
        if (grow < M) {
            u32x4 val = *reinterpret_cast<const u32x4*>(&ep[(size_t)row * EPS + col0]);
            if (col0 < 64)
                *reinterpret_cast<u32x4*>(Y1 + (size_t)grow * 64 + col0) = val;
            else
                __builtin_nontemporal_store(val,
                    reinterpret_cast<u32x4*>(Y2 + (size_t)grow * 128 + (col0 - 64)));
        }
    }
}

// ======================= mean aggregation (CSR) =====================
// One wave per node. WIDE gather: 8 lanes x 16B (dwordx4) per 128B row,
// 8 rows in flight per step (halves gather-instruction count vs 8B/lane
// -- the gather is VMEM-address-issue bound, not BW bound: R6 evidence).

__global__ __launch_bounds__(256) void aggr_k(const int2* __restrict__ ose,
                                              const int* __restrict__ ssrc,
                                              const f16* __restrict__ h,
                                              f16* __restrict__ m, int n) {
    int wave = (blockIdx.x * 256 + threadIdx.x) >> 6;
    int lane = threadIdx.x & 63;
    if (wave >= n) return;
    int2 se = ose[wave];
    int s0 = se.x, s1 = se.y;
    const int l8 = lane & 7;    // 16B segment within row
    const int r8 = lane >> 3;   // row slot (8 rows in flight)
    const u32x4* hp = reinterpret_cast<const u32x4*>(h);   // 8 granules/row
    float a0 = 0.f, a1 = 0.f, a2 = 0.f, a3 = 0.f;
    float a4 = 0.f, a5 = 0.f, a6 = 0.f, a7 = 0.f;
    auto accum = [&](u32x4 u) {
        union { u32x4 u; f16 hh[8]; } p; p.u = u;
        a0 += (float)p.hh[0]; a1 += (float)p.hh[1];
        a2 += (float)p.hh[2]; a3 += (float)p.hh[3];
        a4 += (float)p.hh[4]; a5 += (float)p.hh[5];
        a6 += (float)p.hh[6]; a7 += (float)p.hh[7];
    };
    for (int c = s0; c < s1; c += 64) {
        int cn = min(64, s1 - c);
        int myidx = (lane < cn) ? ssrc[c + lane] : 0;
        int t = 0;
        for (; t + 16 <= cn; t += 16) {
            int ia = __shfl(myidx, t + r8);
            int ib = __shfl(myidx, t + 8 + r8);
            u32x4 ua = hp[(size_t)ia * 8 + l8];
            u32x4 ub = hp[(size_t)ib * 8 + l8];
            accum(ua); accum(ub);
        }
        if (t + 8 <= cn) {
            int ia = __shfl(myidx, t + r8);
            accum(hp[(size_t)ia * 8 + l8]);
            t += 8;
        }
        if (t < cn) {
            int r = t + r8;
            int rr = (r < cn) ? r : (cn - 1);
            int ia = __shfl(myidx, rr);
            if (r < cn) accum(hp[(size_t)ia * 8 + l8]);
        }
    }
    // butterfly over row slots (lane bits 3,4,5)
#define RED(d) a0 += __shfl_xor(a0, d); a1 += __shfl_xor(a1, d); \
               a2 += __shfl_xor(a2, d); a3 += __shfl_xor(a3, d); \
               a4 += __shfl_xor(a4, d); a5 += __shfl_xor(a5, d); \
               a6 += __shfl_xor(a6, d); a7 += __shfl_xor(a7, d);
    RED(8) RED(16) RED(32)
#undef RED
    if (lane < 8) {
        float inv = 1.0f / fmaxf((float)(s1 - s0), 1.0f);
        union { u32x4 u; f16 hh[8]; } pk;
        pk.hh[0] = (f16)(a0 * inv); pk.hh[1] = (f16)(a1 * inv);
        pk.hh[2] = (f16)(a2 * inv); pk.hh[3] = (f16)(a3 * inv);
        pk.hh[4] = (f16)(a4 * inv); pk.hh[5] = (f16)(a5 * inv);
        pk.hh[6] = (f16)(a6 * inv); pk.hh[7] = (f16)(a7 * inv);
        reinterpret_cast<u32x4*>(m + (size_t)wave * 64)[l8] = pk.u;
    }
}

// ========= fused combine1 + GEMM2: x1 lives only in LDS =============
// Phase 1: x1_tile = relu(P + M@Wmt1)   (64 x 128, K=64, 2 MFMA steps)
// Phase 2: [h2 | p2] = x1_tile @ Wt2 + bc2  (K=128, BK=32 loop)

__global__ __launch_bounds__(256) void comb_gemm_k(const f16* __restrict__ Mb,  // [M][64]
                                                   const f16* __restrict__ Wmt, // [128][64]
                                                   const f16* __restrict__ P,   // [M][128]
                                                   const f16* __restrict__ Wt2, // [128][128]
                                                   const float* __restrict__ bc2,
                                                   f16* __restrict__ H2,        // [M][64]
                                                   f16* __restrict__ P2,        // [M][64]
                                                   int M) {
    constexpr int BM = 64, ASTR = 72, TSTR = 136, BSTR = 40;
    constexpr int BN1 = 128, NB1 = 4;
    constexpr int NB2c = 4;
    // LDS: phase1 As[64*72] @0 (9216B), Bs1[128*72] @9216 (18432B) = 27648
    //      phase2 tile[64*136] @0 (17408B), Bs2[128*40] @17408 (10240B) = 27648
    __shared__ __align__(16) char smem[27648];
    f16* As  = reinterpret_cast<f16*>(smem);
    f16* Bs1 = reinterpret_cast<f16*>(smem + (size_t)BM * ASTR * 2);
    f16* tile = reinterpret_cast<f16*>(smem);
    f16* Bs2 = reinterpret_cast<f16*>(smem + (size_t)BM * TSTR * 2);
    const int tid  = threadIdx.x;
    const int wave = tid >> 6, lane = tid & 63;
    const int wr = wave >> 1, wc = wave & 1;
    const int quad = lane >> 4, l16 = lane & 15;
    const int row0 = blockIdx.x * BM;

    // ---- phase 1 staging ----
#pragma unroll
    for (int fid = tid; fid < 512; fid += 256) {
        int row = fid >> 3, s = fid & 7;
        int grow = row0 + row; if (grow >= M) grow = M - 1;
        *reinterpret_cast<u32x4*>(&As[row * ASTR + s * 8]) =
            *reinterpret_cast<const u32x4*>(Mb + (size_t)grow * 64 + s * 8);
    }
#pragma unroll
    for (int fid = tid; fid < BN1 * 8; fid += 256) {
        int n = fid >> 3, s = fid & 7;
        *reinterpret_cast<u32x4*>(&Bs1[n * ASTR + s * 8]) =
            *reinterpret_cast<const u32x4*>(Wmt + (size_t)n * 64 + s * 8);
    }
    __syncthreads();

    f32x4 acc[2][NB1];
#pragma unroll
    for (int i = 0; i < 2; i++)
#pragma unroll
        for (int j = 0; j < NB1; j++) acc[i][j] = (f32x4)(0.f);
#pragma unroll
    for (int ks = 0; ks < 2; ks++) {
        f16x8 af[2], bf[NB1];
#pragma unroll
        for (int rb = 0; rb < 2; rb++) {
            int row = wr * 32 + rb * 16 + l16;
            af[rb] = *reinterpret_cast<const f16x8*>(&As[row * ASTR + ks * 32 + quad * 8]);
        }
#pragma unroll
        for (int cb = 0; cb < NB1; cb++) {
            int n = wc * 64 + cb * 16 + l16;
            bf[cb] = *reinterpret_cast<const f16x8*>(&Bs1[n * ASTR + ks * 32 + quad * 8]);
        }
#pragma unroll
        for (int rb = 0; rb < 2; rb++)
#pragma unroll
            for (int cb = 0; cb < NB1; cb++)
                acc[rb][cb] = __builtin_amdgcn_mfma_f32_16x16x32_f16(af[rb], bf[cb], acc[rb][cb], 0, 0, 0);
    }
    __syncthreads();

    // ---- x1 tile: relu(P + acc), f16 ----
#pragma unroll
    for (int rb = 0; rb < 2; rb++) {
#pragma unroll
        for (int cb = 0; cb < NB1; cb++) {
            int col = wc * 64 + cb * 16 + l16;
#pragma unroll
            for (int r = 0; r < 4; r++) {
                int lrow = wr * 32 + rb * 16 + quad * 4 + r;
                int grow = row0 + lrow;
                float pv = (grow < M) ? (float)P[(size_t)grow * 128 + col] : 0.f;
                tile[(size_t)lrow * TSTR + col] = (f16)fmaxf(acc[rb][cb][r] + pv, 0.f);
            }
        }
    }

    // ---- phase 2: [h2|p2] = tile @ Wt2 + bc2, K=128 ----
    f32x4 acc2[2][NB2c];
#pragma unroll
    for (int i = 0; i < 2; i++)
#pragma unroll
        for (int j = 0; j < NB2c; j++) acc2[i][j] = (f32x4)(0.f);

    u32x4 bReg[2];
    auto loadB2 = [&](int kk) {
#pragma unroll
        for (int i = 0; i < 2; i++) {
            int fid = tid + i * 256;
            int n = fid >> 2, s = fid & 3;
            bReg[i] = *reinterpret_cast<const u32x4*>(Wt2 + (size_t)n * 128 + kk + s * 8);
        }
    };
    loadB2(0);
    for (int kk = 0; kk < 128; kk += 32) {
#pragma unroll
        for (int i = 0; i < 2; i++) {
            int fid = tid + i * 256;
            int n = fid >> 2, s = fid & 3;
            *reinterpret_cast<u32x4*>(&Bs2[n * BSTR + s * 8]) = bReg[i];
        }
        __syncthreads();           // orders tile writes before tile reads too
        if (kk + 32 < 128) loadB2(kk + 32);
        f16x8 af[2], bf[NB2c];
#pragma unroll
        for (int rb = 0; rb < 2; rb++) {
            int row = wr * 32 + rb * 16 + l16;
            af[rb] = *reinterpret_cast<const f16x8*>(&tile[(size_t)row * TSTR + kk + quad * 8]);
        }
#pragma unroll
        for (int cb = 0; cb < NB2c; cb++) {
            int n = wc * 64 + cb * 16 + l16;
            bf[cb] = *reinterpret_cast<const f16x8*>(&Bs2[n * BSTR + quad * 8]);
        }
#pragma unroll
        for (int rb = 0; rb < 2; rb++)
#pragma unroll
            for (int cb = 0; cb < NB2c; cb++)
                acc2[rb][cb] = __builtin_amdgcn_mfma_f32_16x16x32_f16(af[rb], bf[cb], acc2[rb][cb], 0, 0, 0);
        __syncthreads();
    }

    // ---- epilogue: bias (no act) -> LDS (over tile) -> stores ----
    f16* ep = tile;
#pragma unroll
    for (int rb = 0; rb < 2; rb++) {
#pragma unroll
        for (int cb = 0; cb < NB2c; cb++) {
            int col = wc * 64 + cb * 16 + l16;
            float bv = bc2[col];
#pragma unroll
            for (int r = 0; r < 4; r++) {
                int lrow = wr * 32 + rb * 16 + quad * 4 + r;
                ep[(size_t)lrow * TSTR + col] = (f16)(acc2[rb][cb][r] + bv);
            }
        }
    }
    __syncthreads();
#pragma unroll
    for (int p = 0; p < 4; p++) {                 // 64 rows * 16 chunks / 256
        int fid = p * 256 + tid;
        int row = fid >> 4, c = fid & 15, col0 = c * 8;
        int grow = row0 + row;
        if (grow < M) {
            u32x4 val = *reinterpret_cast<const u32x4*>(&ep[(size_t)row * TSTR + col0]);
            if (col0 < 64)
                *reinterpret_cast<u32x4*>(H2 + (size_t)grow * 64 + col0) = val;
            else
                __builtin_nontemporal_store(val,
                    reinterpret_cast<u32x4*>(P2 + (size_t)grow * 64 + (col0 - 64)));
        }
    }
}

// ============ combine2 + head: out = MLP(relu(P2 + M@Wmt2)) =========

__global__ __launch_bounds__(256) void comb_head_k(const f16* __restrict__ Mb,  // [M][64]
                                                   const f16* __restrict__ Wmt, // [64][64]
                                                   const f16* __restrict__ P,   // [M][64]
                                                   const float* __restrict__ Wl1,
                                                   const float* __restrict__ bl1,
                                                   const float* __restrict__ Wl2,
                                                   const float* __restrict__ bl2,
                                                   float* __restrict__ out, int M) {
    constexpr int BM = 64, ASTR = 72, BN = 64, NB = 2;
    constexpr int EPS = BN + 8;
    constexpr size_t SZ_A = (size_t)BM * ASTR * 2;
    constexpr size_t SM_AB = SZ_A + (size_t)BN * ASTR * 2;
    constexpr size_t SM_EP = (size_t)BM * EPS * 2;
    constexpr size_t SM_CORE = SM_AB > SM_EP ? SM_AB : SM_EP;
    __shared__ __align__(16) char smem[SM_CORE + (2048 + 64) * 4];
    f16* As = reinterpret_cast<f16*>(smem);
    f16* Bs = reinterpret_cast<f16*>(smem + SZ_A);
    const int tid  = threadIdx.x;
    const int wave = tid >> 6, lane = tid & 63;
    const int wr = wave >> 1, wc = wave & 1;
    const int quad = lane >> 4, l16 = lane & 15;
    const int row0 = blockIdx.x * BM;

#pragma unroll
    for (int fid = tid; fid < 512; fid += 256) {
        int row = fid >> 3, s = fid & 7;
        int grow = row0 + row; if (grow >= M) grow = M - 1;
        *reinterpret_cast<u32x4*>(&As[row * ASTR + s * 8]) =
            *reinterpret_cast<const u32x4*>(Mb + (size_t)grow * 64 + s * 8);
    }
    for (int fid = tid; fid < BN * 8; fid += 256) {
        int n = fid >> 3, s = fid & 7;
        *reinterpret_cast<u32x4*>(&Bs[n * ASTR + s * 8]) =
            *reinterpret_cast<const u32x4*>(Wmt + (size_t)n * 64 + s * 8);
    }
    {
        float* w1s = reinterpret_cast<float*>(smem + SM_CORE);
        for (int t2 = tid; t2 < 2048; t2 += 256) w1s[t2] = Wl1[t2];
        if (tid < 32) { w1s[2048 + tid] = bl1[tid]; w1s[2048 + 32 + tid] = Wl2[tid]; }
    }
    __syncthreads();

    f32x4 acc[2][NB];
#pragma unroll
    for (int i = 0; i < 2; i++)
#pragma unroll
        for (int j = 0; j < NB; j++) acc[i][j] = (f32x4)(0.f);
#pragma unroll
    for (int ks = 0; ks < 2; ks++) {
        f16x8 af[2], bf[NB];
#pragma unroll
        for (int rb = 0; rb < 2; rb++) {
            int row = wr * 32 + rb * 16 + l16;
            af[rb] = *reinterpret_cast<const f16x8*>(&As[row * ASTR + ks * 32 + quad * 8]);
        }
#pragma unroll
        for (int cb = 0; cb < NB; cb++) {
            int n = wc * 32 + cb * 16 + l16;
            bf[cb] = *reinterpret_cast<const f16x8*>(&Bs[n * ASTR + ks * 32 + quad * 8]);
        }
#pragma unroll
        for (int rb = 0; rb < 2; rb++)
#pragma unroll
            for (int cb = 0; cb < NB; cb++)
                acc[rb][cb] = __builtin_amdgcn_mfma_f32_16x16x32_f16(af[rb], bf[cb], acc[rb][cb], 0, 0, 0);
    }
    __syncthreads();

    f16* ep = reinterpret_cast<f16*>(smem);
#pragma unroll
    for (int rb = 0; rb < 2; rb++) {
#pragma unroll
        for (int cb = 0; cb < NB; cb++) {
            int col = wc * 32 + cb * 16 + l16;
#pragma unroll
            for (int r = 0; r < 4; r++) {
                int lrow = wr * 32 + rb * 16 + quad * 4 + r;
                int grow = row0 + lrow;
                float pv = (grow < M) ? (float)P[(size_t)grow * 64 + col] : 0.f;
                ep[(size_t)lrow * EPS + col] = (f16)fmaxf(acc[rb][cb][r] + pv, 0.f);
            }
        }
    }
    __syncthreads();

    float* w1s = reinterpret_cast<float*>(smem + SM_CORE);
    float* b1s = w1s + 2048;
    float* w2s = b1s + 32;
    int row = tid >> 2, part = tid & 3;
    const f16* eprow = ep + (size_t)row * EPS;
    float hj[8];
#pragma unroll
    for (int j = 0; j < 8; j++) hj[j] = b1s[part * 8 + j];
    for (int k = 0; k < 64; k++) {
        float v = (float)eprow[k];
        const float* wrow = &w1s[k * 32 + part * 8];
#pragma unroll
        for (int j = 0; j < 8; j++) hj[j] += v * wrow[j];
    }
    float o = 0.f;
#pragma unroll
    for (int j = 0; j < 8; j++) o += fmaxf(hj[j], 0.f) * w2s[part * 8 + j];
    o += __shfl_xor(o, 1);
    o += __shfl_xor(o, 2);
    int grow = row0 + row;
    if (part == 0 && grow < M) out[grow] = o + bl2[0];
}

// ============================ launch ================================

extern "C" void kernel_launch(void* const* d_in, const int* in_sizes, int n_in,
                              void* d_out, int out_size, void* d_ws, size_t ws_size,
                              hipStream_t stream) {
    const float* x   = (const float*)d_in[0];
    const int*   ei  = (const int*)d_in[1];
    const float* W1a = (const float*)d_in[3];
    const float* b1a = (const float*)d_in[4];
    const float* W1b = (const float*)d_in[5];
    const float* b1b = (const float*)d_in[6];
    const float* W2a = (const float*)d_in[7];
    const float* b2a = (const float*)d_in[8];
    const float* W2b = (const float*)d_in[9];
    const float* b2b = (const float*)d_in[10];
    const float* Wl1 = (const float*)d_in[11];
    const float* bl1 = (const float*)d_in[12];
    const float* Wl2 = (const float*)d_in[13];
    const float* bl2 = (const float*)d_in[14];

    const int N = in_sizes[0] / IN_DIM;
    const int E = in_sizes[1] / 2;
    const int* srcp = ei;
    const int* dstp = ei + E;

    char* ws = (char*)d_ws;
    size_t off = 0;
    auto alloc = [&](size_t bytes) -> char* {
        char* p = ws + off;
        off = (off + bytes + 255) & ~(size_t)255;
        return p;
    };
    int NB2 = (N + 255) / 256;
    int*      bcur  = (int*)alloc(512 * 4);
    unsigned* bedge = (unsigned*)alloc((size_t)NB2 * CAP * 4);
    int2*     ose   = (int2*)alloc((size_t)N * 8);
    f16*      hbuf  = (f16*)alloc((size_t)N * 64 * 2);
    f16*      mbuf  = (f16*)alloc((size_t)N * 64 * 2);
    f16*      pbuf  = (f16*)alloc((size_t)N * 128 * 2);
    f16*      h2    = (f16*)alloc((size_t)N * 64 * 2);
    f16*      p2    = (f16*)alloc((size_t)N * 64 * 2);
    f16*      Wt1   = (f16*)alloc(192 * 256 * 2);
    f16*      Wt2   = (f16*)alloc(128 * 128 * 2);
    f16*      Wmt1  = (f16*)alloc(128 * 64 * 2);
    f16*      Wmt2  = (f16*)alloc(64 * 64 * 2);
    float*    bc1   = (float*)alloc(192 * 4);
    float*    bc2   = (float*)alloc(128 * 4);
    (void)ws_size;

    // ---- prep (zero bcur + weights) then CSR build ----
    prep_k<<<306, 256, 0, stream>>>(W1a, W1b, W2a, W2b, b1a, b1b, b2a, b2b,
                                    Wt1, Wt2, Wmt1, Wmt2, bc1, bc2, bcur);
    int ebk = (E + EPB - 1) / EPB;
    bucket_scatter_k<<<ebk, 256, 0, stream>>>(srcp, dstp, bcur, bedge, E);
    fine_sort_k<<<NB2, 256, 0, stream>>>(bedge, bcur, ose, N);

    int mb = (N + 63) / 64;
    int ab = (N * 64 + 255) / 256;     // one wave per node
    const int* ssrc = (const int*)bedge;

    // ---- conv1: x -> [h|p]; wide gather; combine1+gemm2 fused ----
    gemm_fused192<<<mb, 256, 0, stream>>>(x, Wt1, bc1, hbuf, pbuf, N);
    aggr_k<<<ab, 256, 0, stream>>>(ose, ssrc, hbuf, mbuf, N);
    comb_gemm_k<<<mb, 256, 0, stream>>>(mbuf, Wmt1, pbuf, Wt2, bc2, h2, p2, N);

    // ---- conv2 tail: wide gather; combine2+head ----
    aggr_k<<<ab, 256, 0, stream>>>(ose, ssrc, h2, mbuf, N);
    comb_head_k<<<mb, 256, 0, stream>>>(mbuf, Wmt2, p2, Wl1, bl1, Wl2, bl2,
                                        (float*)d_out, N);
}